// Round 9
// baseline (255.211 us; speedup 1.0000x reference)
//
#include <hip/hip_runtime.h>
#include <hip/hip_bf16.h>

// Shapes (fixed): B=4, Q=K=1024, D=256, H=8, C=32.
// WORLD CONFIRMED fp32 inputs/outputs; bf16 internals pass (absmax 3.9e-3).
// MFMA fragment mappings HW-proven: A[m=lane&15][k=quad*8+j],
// B[k=quad*8+j][n=lane&15], C/D: col=lane&15, row=quad*4+reg.
//
// LEDGER: R0 252.7 | R1 attn reg-pipeline 255.3 (NEUTRAL) | R4 TLP 260.2
// (NEUTRAL) | R6 fused+spin-bar 405 (REGRESS, reverted) | R7 amplification:
// attn=45us dominant (HBM ~50%, MfmaUtil 4%, VALU 30%, Occ 21%, conflicts
// 11%); proj<15.4, outproj<9.6, transpose<3.2; wall = 154us harness fills
// + ~72us kernels + ~27us gaps | R8 attn QBLK32/K-parity/2x-occ 251.0
// (best, but -1.7 ~ noise).
//
// R9: attack the one untried mechanism on the dominant kernel - the
// bias_pair LOAD PATH. Was: 16 scattered scalar f32 loads/wave/tile
// (4-row x 64B segments) consumed directly as MFMA C-init => exposed HBM
// latency per tile, 1/4 bytes-per-instruction. Now: cooperative LDS stage
// of the block's 32x128 f32 bias subtile per iteration (256 thr x 4
// float4, perfectly coalesced), consumed as near-conflict-free LDS scalar
// reads (stride 132: quad pairs 2-way = free). Staging overlaps K/V stage
// in the same barrier structure. LDS 28.5->45.4KB (3 blk/CU).
// proj/outproj/transpose: exact R0 bodies. Everything else = R8.
//
// Workspace (byte offsets into d_ws, 13.3 MB):
//   wt   5x[256][256] bf16 @ 0        (wq,wk,wv,wg,wo transposed: wt[n][k])
//   qhb  [B,H,Q,C]   bf16 @ 655360   (q/sqrt(C))
//   khb  [B,H,K,C]   bf16 @ 2752512
//   vhb  [B,H,K,C]   bf16 @ 4849664
//   og   [B,Q,256]   bf16 @ 6946816  (gated attention output)
//   gws  [B,Q,256]   fp32 @ 9043968  (sigmoid gate)

typedef short bf16x8 __attribute__((ext_vector_type(8)));
typedef float f32x4 __attribute__((ext_vector_type(4)));

__device__ __forceinline__ unsigned short f2bf(float f) {
  __hip_bfloat16 hb = __float2bfloat16(f);
  return *reinterpret_cast<const unsigned short*>(&hb);
}

// ------------- Kernel 0: transpose + fp32->bf16 convert weights ----------
// grid 80 = 5 weights x 16 (64x64 tiles). wt[n][k] = bf16(W[k][n]).
__global__ __launch_bounds__(256) void transpose_conv(
    const float* __restrict__ wq, const float* __restrict__ wk,
    const float* __restrict__ wv, const float* __restrict__ wg,
    const float* __restrict__ wo, unsigned short* __restrict__ wt) {
  __shared__ float t[64][65];
  const int widx = blockIdx.x >> 4;
  const int tile = blockIdx.x & 15;
  const float* src = widx == 0 ? wq : widx == 1 ? wk
                     : widx == 2 ? wv : widx == 3 ? wg : wo;
  unsigned short* dst = wt + widx * 65536;
  const int r0 = (tile >> 2) * 64, c0 = (tile & 3) * 64;
  const int tr = threadIdx.x >> 4;
  const int tc4 = (threadIdx.x & 15) * 4;
#pragma unroll
  for (int i = 0; i < 4; ++i) {
    const float4 u = *reinterpret_cast<const float4*>(
        src + (size_t)(r0 + tr + i * 16) * 256 + c0 + tc4);
    t[tr + i * 16][tc4 + 0] = u.x;
    t[tr + i * 16][tc4 + 1] = u.y;
    t[tr + i * 16][tc4 + 2] = u.z;
    t[tr + i * 16][tc4 + 3] = u.w;
  }
  __syncthreads();
#pragma unroll
  for (int i = 0; i < 4; ++i) {
    const int rr = tr + i * 16;  // dst row (= src col)
    ushort4 o;
    o.x = f2bf(t[tc4 + 0][rr]);
    o.y = f2bf(t[tc4 + 1][rr]);
    o.z = f2bf(t[tc4 + 2][rr]);
    o.w = f2bf(t[tc4 + 3][rr]);
    *reinterpret_cast<ushort4*>(dst + (size_t)(c0 + rr) * 256 + r0 + tc4) = o;
  }
}

// ------------- Kernel 1: input projections (MFMA) ------------------------
// grid (256, 2): x = 16-row m-tile, y = side (0: wq/wg, 1: wk/wv).
// Wave w covers n-quarter w*64 (4 ntiles) x 2 weights. Outputs bf16.
__global__ __launch_bounds__(256) void proj_mfma(
    const float* __restrict__ q_x, const float* __restrict__ kv_x,
    const unsigned short* __restrict__ wt, const float* __restrict__ bg,
    unsigned short* __restrict__ qhb, unsigned short* __restrict__ khb,
    unsigned short* __restrict__ vhb, float* __restrict__ gws) {
  const int side = blockIdx.y;
  const int m0 = blockIdx.x * 16;
  const int lane = threadIdx.x & 63;
  const int n0 = (threadIdx.x >> 6) * 64;
  const int mrow = lane & 15;
  const int quad = lane >> 4;
  const float* X = side ? kv_x : q_x;
  const unsigned short* W0 = wt + (side ? 1 : 0) * 65536;  // wk : wq
  const unsigned short* W1 = wt + (side ? 2 : 3) * 65536;  // wv : wg
  f32x4 acc0[4], acc1[4];
  const f32x4 z = {0.f, 0.f, 0.f, 0.f};
#pragma unroll
  for (int nt = 0; nt < 4; ++nt) { acc0[nt] = z; acc1[nt] = z; }

  for (int k0 = 0; k0 < 256; k0 += 32) {
    const size_t abase = (size_t)(m0 + mrow) * 256 + k0 + quad * 8;
    const float4 a0 = *reinterpret_cast<const float4*>(X + abase);
    const float4 a1 = *reinterpret_cast<const float4*>(X + abase + 4);
    bf16x8 a;
    a[0] = (short)f2bf(a0.x); a[1] = (short)f2bf(a0.y);
    a[2] = (short)f2bf(a0.z); a[3] = (short)f2bf(a0.w);
    a[4] = (short)f2bf(a1.x); a[5] = (short)f2bf(a1.y);
    a[6] = (short)f2bf(a1.z); a[7] = (short)f2bf(a1.w);
#pragma unroll
    for (int nt = 0; nt < 4; ++nt) {
      const size_t wrow = (size_t)(n0 + nt * 16 + mrow) * 256 + k0 + quad * 8;
      const bf16x8 b0 = *reinterpret_cast<const bf16x8*>(W0 + wrow);
      const bf16x8 b1 = *reinterpret_cast<const bf16x8*>(W1 + wrow);
      acc0[nt] = __builtin_amdgcn_mfma_f32_16x16x32_bf16(a, b0, acc0[nt], 0, 0, 0);
      acc1[nt] = __builtin_amdgcn_mfma_f32_16x16x32_bf16(a, b1, acc1[nt], 0, 0, 0);
    }
  }

  const int b = m0 >> 10;
#pragma unroll
  for (int nt = 0; nt < 4; ++nt) {
    const int n = n0 + nt * 16 + mrow;  // output col
    const int h = n >> 5, c = n & 31;
    const float bgv = (side == 0) ? bg[n] : 0.f;
#pragma unroll
    for (int r = 0; r < 4; ++r) {
      const int row = m0 + quad * 4 + r;
      const int qp = row & 1023;
      const size_t o = ((size_t)(b * 8 + h) * 1024 + qp) * 32 + c;
      if (side == 0) {
        qhb[o] = f2bf(acc0[nt][r] * 0.17677669529663689f);  // 1/sqrt(32)
        const float zz = acc1[nt][r] + bgv;
        gws[(size_t)row * 256 + n] = 1.0f / (1.0f + __expf(-zz));
      } else {
        khb[o] = f2bf(acc0[nt][r]);
        vhb[o] = f2bf(acc1[nt][r]);
      }
    }
  }
}

// ------------- Kernel 2: MFMA flash attention + gate (R9) ----------------
// grid 1024 = B*H*(Q/32), 256 threads. Wave wv: qg=wv&1 (rows q0+qg*16..),
// kp=wv>>1 (K-tile parity). Per iter i: cooperatively stage K/V tiles
// 2i,2i+1 (128 k-rows) AND the 32x128 f32 bias_pair subtile (coalesced
// float4 -> LDS, stride 132). Wave processes tile 2i+kp; bias C-init read
// from LDS (2-way max = free). 8 iters. End: flash-merge (m,l,oa) across
// K-parity pairs via LDS; kp=0 stores.
__global__ __launch_bounds__(256) void attn_mfma(
    const unsigned short* __restrict__ qhb,
    const unsigned short* __restrict__ khb,
    const unsigned short* __restrict__ vhb,
    const float* __restrict__ bias_mask,
    const float* __restrict__ bias_pair,
    const float* __restrict__ gws, unsigned short* __restrict__ og) {
  __shared__ unsigned short ks[2][64 * 40];   // K-tile [parity][kpos][c]
  __shared__ unsigned short vsT[2][32 * 72];  // V-tile T [parity][c][kpos]
  __shared__ unsigned short ps[64 * 72];      // P bf16, per-wave 16-row bands
  __shared__ float bsh[32 * 132];             // bias subtile [qrow][kcol]
  const int x = blockIdx.x;
  const int b = x >> 8, h = (x >> 5) & 7, q0 = (x & 31) * 32;
  const int tid = threadIdx.x;
  const int wv = tid >> 6, lane = tid & 63, quad = lane >> 4, lr = lane & 15;
  const int qg = wv & 1;   // q-row half within the 32-row block
  const int kp = wv >> 1;  // K-tile parity this wave owns
  const int bh = b * 8 + h;

  // A-frag of Q for this wave (held in regs for all 8 K-tile iters).
  const bf16x8 aq = *reinterpret_cast<const bf16x8*>(
      qhb + ((size_t)bh * 1024 + q0 + qg * 16 + lr) * 32 + quad * 8);

  float m[4], l[4];
  f32x4 oa[2];
  const f32x4 zero4 = {0.f, 0.f, 0.f, 0.f};
  oa[0] = zero4; oa[1] = zero4;
#pragma unroll
  for (int r = 0; r < 4; ++r) { m[r] = -3e30f; l[r] = 0.f; }

  const float* bm = bias_mask + (size_t)b * 1024;
  const float* bpb = bias_pair + ((size_t)bh * 1024 + q0) * 1024;
  const unsigned short* kbase = khb + (size_t)bh * 32768;
  const unsigned short* vbase = vhb + (size_t)bh * 32768;

  for (int i = 0; i < 8; ++i) {
    __syncthreads();  // protect ks/vsT/bsh reuse across iterations
    // ---- stage K/V tiles 2i,2i+1 (128 k-rows x 32 c), 2 chunks/thread ----
#pragma unroll
    for (int j = 0; j < 2; ++j) {
      const int ch = tid * 2 + j;
      const int rr = ch >> 2, c8 = (ch & 3) * 8;
      const int p = rr >> 6, r64 = rr & 63;
      const size_t src = (size_t)(i * 128 + rr) * 32 + c8;
      *reinterpret_cast<bf16x8*>(&ks[p][r64 * 40 + c8]) =
          *reinterpret_cast<const bf16x8*>(kbase + src);
      const bf16x8 vvv = *reinterpret_cast<const bf16x8*>(vbase + src);
#pragma unroll
      for (int j2 = 0; j2 < 8; ++j2)
        vsT[p][(c8 + j2) * 72 + r64] = (unsigned short)vvv[j2];
    }
    // ---- stage bias subtile: 32 q-rows x 128 k-cols f32, coalesced ----
#pragma unroll
    for (int j = 0; j < 4; ++j) {
      const int s = tid + 256 * j;
      const int row = s >> 5, c4 = (s & 31) * 4;
      const float4 bv = *reinterpret_cast<const float4*>(
          bpb + (size_t)row * 1024 + i * 128 + c4);
      *reinterpret_cast<float4*>(&bsh[row * 132 + c4]) = bv;
    }
    __syncthreads();

    const int kk0 = (i * 2 + kp) * 64;  // this wave's K-tile origin

    // ---- scores: C = bias (LDS) + mask, then QK^T MFMA ----
    f32x4 s[4];
    float mk[4];
#pragma unroll
    for (int nt = 0; nt < 4; ++nt) mk[nt] = bm[kk0 + 16 * nt + lr];
#pragma unroll
    for (int nt = 0; nt < 4; ++nt) {
#pragma unroll
      for (int r = 0; r < 4; ++r)
        s[nt][r] = bsh[(qg * 16 + quad * 4 + r) * 132 + kp * 64 + 16 * nt + lr]
                   + mk[nt];
      const bf16x8 bk = *reinterpret_cast<const bf16x8*>(
          &ks[kp][(16 * nt + lr) * 40 + quad * 8]);
      s[nt] = __builtin_amdgcn_mfma_f32_16x16x32_bf16(aq, bk, s[nt], 0, 0, 0);
    }

    // ---- online softmax (rows quad*4+r, reduce over 16-lane group) ----
#pragma unroll
    for (int r = 0; r < 4; ++r) {
      float mx = fmaxf(fmaxf(s[0][r], s[1][r]), fmaxf(s[2][r], s[3][r]));
      mx = fmaxf(mx, __shfl_xor(mx, 1));
      mx = fmaxf(mx, __shfl_xor(mx, 2));
      mx = fmaxf(mx, __shfl_xor(mx, 4));
      mx = fmaxf(mx, __shfl_xor(mx, 8));
      const float mn = fmaxf(m[r], mx);
      const float alpha = __expf(m[r] - mn);
      float rs = 0.f;
#pragma unroll
      for (int nt = 0; nt < 4; ++nt) {
        s[nt][r] = __expf(s[nt][r] - mn);
        rs += s[nt][r];
      }
      rs += __shfl_xor(rs, 1);
      rs += __shfl_xor(rs, 2);
      rs += __shfl_xor(rs, 4);
      rs += __shfl_xor(rs, 8);
      l[r] = l[r] * alpha + rs;
      m[r] = mn;
      oa[0][r] *= alpha;
      oa[1][r] *= alpha;
      const int ri = wv * 16 + quad * 4 + r;
#pragma unroll
      for (int nt = 0; nt < 4; ++nt)
        ps[ri * 72 + 16 * nt + lr] = f2bf(s[nt][r]);
    }
    // ps is per-wave; drain scatter writes before A-frag reads.
    asm volatile("s_waitcnt lgkmcnt(0)" ::: "memory");

    // ---- PV: A = P (own band), B = V^T (LDS buffer kp) ----
#pragma unroll
    for (int k0i = 0; k0i < 2; ++k0i) {
      const bf16x8 ap = *reinterpret_cast<const bf16x8*>(
          &ps[(wv * 16 + lr) * 72 + k0i * 32 + quad * 8]);
#pragma unroll
      for (int nt2 = 0; nt2 < 2; ++nt2) {
        const bf16x8 bv = *reinterpret_cast<const bf16x8*>(
            &vsT[kp][(nt2 * 16 + lr) * 72 + k0i * 32 + quad * 8]);
        oa[nt2] = __builtin_amdgcn_mfma_f32_16x16x32_bf16(ap, bv, oa[nt2], 0, 0, 0);
      }
    }
  }

  // ---- flash-merge across K-parity pairs (waves 2,3 -> waves 0,1) ----
  float* mrg = reinterpret_cast<float*>(ks);  // 8.1 KB scratch in ks region
  __syncthreads();  // last PV reads done before overwriting ks
  if (kp == 1) {
    const int base = (qg * 64 + lane) * 16;
#pragma unroll
    for (int r = 0; r < 4; ++r) {
      mrg[base + r] = m[r];
      mrg[base + 4 + r] = l[r];
      mrg[base + 8 + r] = oa[0][r];
      mrg[base + 12 + r] = oa[1][r];
    }
  }
  __syncthreads();
  if (kp == 0) {
    const int base = (qg * 64 + lane) * 16;
#pragma unroll
    for (int r = 0; r < 4; ++r) {
      const float pm = mrg[base + r];
      const float pl = mrg[base + 4 + r];
      const float po0 = mrg[base + 8 + r];
      const float po1 = mrg[base + 12 + r];
      const float mn = fmaxf(m[r], pm);
      const float a0 = __expf(m[r] - mn);
      const float a1 = __expf(pm - mn);
      const float inv = 1.0f / (l[r] * a0 + pl * a1);
      const int qr = q0 + qg * 16 + quad * 4 + r;
      const size_t obase = ((size_t)b * 1024 + qr) * 256 + h * 32;
      const float o0 = oa[0][r] * a0 + po0 * a1;
      og[obase + lr] = f2bf(o0 * inv * gws[obase + lr]);
      const float o1 = oa[1][r] * a0 + po1 * a1;
      og[obase + 16 + lr] = f2bf(o1 * inv * gws[obase + 16 + lr]);
    }
  }
}

// ------------- Kernel 3: output projection (MFMA), fp32 out --------------
// grid 256: x = 16-row m-tile; wave w covers n-quarter w*64 (4 ntiles).
__global__ __launch_bounds__(256) void outproj_mfma(
    const unsigned short* __restrict__ og,
    const unsigned short* __restrict__ wt,
    const float* __restrict__ bo, float* __restrict__ out) {
  const int m0 = blockIdx.x * 16;
  const int lane = threadIdx.x & 63;
  const int n0 = (threadIdx.x >> 6) * 64;
  const int mrow = lane & 15;
  const int quad = lane >> 4;
  const unsigned short* W = wt + 4 * 65536;  // wo^T
  f32x4 acc[4];
  const f32x4 z = {0.f, 0.f, 0.f, 0.f};
#pragma unroll
  for (int nt = 0; nt < 4; ++nt) acc[nt] = z;

  for (int k0 = 0; k0 < 256; k0 += 32) {
    const bf16x8 a = *reinterpret_cast<const bf16x8*>(
        og + (size_t)(m0 + mrow) * 256 + k0 + quad * 8);
#pragma unroll
    for (int nt = 0; nt < 4; ++nt) {
      const bf16x8 b = *reinterpret_cast<const bf16x8*>(
          W + (size_t)(n0 + nt * 16 + mrow) * 256 + k0 + quad * 8);
      acc[nt] = __builtin_amdgcn_mfma_f32_16x16x32_bf16(a, b, acc[nt], 0, 0, 0);
    }
  }

#pragma unroll
  for (int nt = 0; nt < 4; ++nt) {
    const int n = n0 + nt * 16 + mrow;
    const float bov = bo[n];
#pragma unroll
    for (int r = 0; r < 4; ++r) {
      const int row = m0 + quad * 4 + r;
      out[(size_t)row * 256 + n] = acc[nt][r] + bov;
    }
  }
}

extern "C" void kernel_launch(void* const* d_in, const int* in_sizes, int n_in,
                              void* d_out, int out_size, void* d_ws,
                              size_t ws_size, hipStream_t stream) {
  (void)in_sizes; (void)n_in; (void)out_size; (void)ws_size;
  const float* q_x = (const float*)d_in[0];
  const float* kv_x = (const float*)d_in[1];
  const float* bias_mask = (const float*)d_in[2];
  const float* bias_pair = (const float*)d_in[3];
  const float* wq = (const float*)d_in[4];
  const float* wk = (const float*)d_in[5];
  const float* wv = (const float*)d_in[6];
  const float* wg = (const float*)d_in[7];
  const float* bg = (const float*)d_in[8];
  const float* wo = (const float*)d_in[9];
  const float* bo = (const float*)d_in[10];

  char* wsb = (char*)d_ws;
  unsigned short* wt  = (unsigned short*)(wsb);            // 640 KB
  unsigned short* qhb = (unsigned short*)(wsb + 655360);   // 2 MB
  unsigned short* khb = (unsigned short*)(wsb + 2752512);  // 2 MB
  unsigned short* vhb = (unsigned short*)(wsb + 4849664);  // 2 MB
  unsigned short* og  = (unsigned short*)(wsb + 6946816);  // 2 MB
  float* gws          = (float*)(wsb + 9043968);           // 4 MB

  transpose_conv<<<80, 256, 0, stream>>>(wq, wk, wv, wg, wo, wt);
  proj_mfma<<<dim3(256, 2), 256, 0, stream>>>(q_x, kv_x, wt, bg, qhb, khb,
                                              vhb, gws);
  attn_mfma<<<1024, 256, 0, stream>>>(qhb, khb, vhb, bias_mask, bias_pair,
                                      gws, og);
  outproj_mfma<<<256, 256, 0, stream>>>(og, wt, bo, (float*)d_out);
}

// Round 10
// 250.408 us; speedup vs baseline: 1.0192x; 1.0192x over previous
//
#include <hip/hip_runtime.h>
#include <hip/hip_bf16.h>

// Shapes (fixed): B=4, Q=K=1024, D=256, H=8, C=32.
// WORLD CONFIRMED fp32 inputs/outputs; bf16 internals pass (absmax 3.9e-3).
// MFMA fragment mappings HW-proven: A[m=lane&15][k=quad*8+j],
// B[k=quad*8+j][n=lane&15], C/D: col=lane&15, row=quad*4+reg.
//
// LEDGER: R0 252.7 | R1 attn reg-pipeline 255.3 NEUTRAL | R4 TLP 260.2
// NEUTRAL | R6 fused+spin-bar 405 REGRESS | R7 amplification: attn=45us
// dominant (HBM ~50%, Occ 21%, MfmaUtil 4%, VALU 30%); wall = ~154us
// harness fills + ~72us kernels + gaps | R8 QBLK32/K-parity/2x-occ 251.0
// BEST | R9 bias->LDS coalesced 255.2 NEUTRAL-NEG (occ 4->3 blk/CU).
//
// R10 = R8 + the one untried guide-mandated mechanism (Common Mistake #1):
// __builtin_amdgcn_global_load_lds for K-tile staging. ks stride 40->32
// shorts => [2][64][32] layout is byte-linear in source row (row rr at
// byte 64*rr), so wave-uniform-dest + lane*16B matches the global layout
// exactly: wave w issues 2 DMAs (16 rows = 1024B each) for rows w*32..+31.
// Removes K's VGPR round-trip + lgkm chain from staging; vm queue fills
// fire-and-forget. V stays reg-staged (transpose scatter can't DMA).
// LDS 28.7->26.6KB. K-read pattern becomes contiguous-1024B (conflict-
// free). Everything else byte-identical to R8.
//
// Workspace (byte offsets into d_ws, 13.3 MB):
//   wt   5x[256][256] bf16 @ 0        (wq,wk,wv,wg,wo transposed: wt[n][k])
//   qhb  [B,H,Q,C]   bf16 @ 655360   (q/sqrt(C))
//   khb  [B,H,K,C]   bf16 @ 2752512
//   vhb  [B,H,K,C]   bf16 @ 4849664
//   og   [B,Q,256]   bf16 @ 6946816  (gated attention output)
//   gws  [B,Q,256]   fp32 @ 9043968  (sigmoid gate)

typedef short bf16x8 __attribute__((ext_vector_type(8)));
typedef float f32x4 __attribute__((ext_vector_type(4)));

__device__ __forceinline__ unsigned short f2bf(float f) {
  __hip_bfloat16 hb = __float2bfloat16(f);
  return *reinterpret_cast<const unsigned short*>(&hb);
}

// HBM -> LDS direct DMA, 16 B per lane. Dest is wave-uniform base;
// HW adds lane*16. Source address is per-lane.
__device__ __forceinline__ void gload_lds16(const unsigned short* g,
                                            unsigned short* l) {
  __builtin_amdgcn_global_load_lds(
      (const __attribute__((address_space(1))) unsigned int*)g,
      (__attribute__((address_space(3))) unsigned int*)l, 16, 0, 0);
}

// ------------- Kernel 0: transpose + fp32->bf16 convert weights ----------
// grid 80 = 5 weights x 16 (64x64 tiles). wt[n][k] = bf16(W[k][n]).
__global__ __launch_bounds__(256) void transpose_conv(
    const float* __restrict__ wq, const float* __restrict__ wk,
    const float* __restrict__ wv, const float* __restrict__ wg,
    const float* __restrict__ wo, unsigned short* __restrict__ wt) {
  __shared__ float t[64][65];
  const int widx = blockIdx.x >> 4;
  const int tile = blockIdx.x & 15;
  const float* src = widx == 0 ? wq : widx == 1 ? wk
                     : widx == 2 ? wv : widx == 3 ? wg : wo;
  unsigned short* dst = wt + widx * 65536;
  const int r0 = (tile >> 2) * 64, c0 = (tile & 3) * 64;
  const int tr = threadIdx.x >> 4;
  const int tc4 = (threadIdx.x & 15) * 4;
#pragma unroll
  for (int i = 0; i < 4; ++i) {
    const float4 u = *reinterpret_cast<const float4*>(
        src + (size_t)(r0 + tr + i * 16) * 256 + c0 + tc4);
    t[tr + i * 16][tc4 + 0] = u.x;
    t[tr + i * 16][tc4 + 1] = u.y;
    t[tr + i * 16][tc4 + 2] = u.z;
    t[tr + i * 16][tc4 + 3] = u.w;
  }
  __syncthreads();
#pragma unroll
  for (int i = 0; i < 4; ++i) {
    const int rr = tr + i * 16;  // dst row (= src col)
    ushort4 o;
    o.x = f2bf(t[tc4 + 0][rr]);
    o.y = f2bf(t[tc4 + 1][rr]);
    o.z = f2bf(t[tc4 + 2][rr]);
    o.w = f2bf(t[tc4 + 3][rr]);
    *reinterpret_cast<ushort4*>(dst + (size_t)(c0 + rr) * 256 + r0 + tc4) = o;
  }
}

// ------------- Kernel 1: input projections (MFMA) ------------------------
// grid (256, 2): x = 16-row m-tile, y = side (0: wq/wg, 1: wk/wv).
// Wave w covers n-quarter w*64 (4 ntiles) x 2 weights. Outputs bf16.
__global__ __launch_bounds__(256) void proj_mfma(
    const float* __restrict__ q_x, const float* __restrict__ kv_x,
    const unsigned short* __restrict__ wt, const float* __restrict__ bg,
    unsigned short* __restrict__ qhb, unsigned short* __restrict__ khb,
    unsigned short* __restrict__ vhb, float* __restrict__ gws) {
  const int side = blockIdx.y;
  const int m0 = blockIdx.x * 16;
  const int lane = threadIdx.x & 63;
  const int n0 = (threadIdx.x >> 6) * 64;
  const int mrow = lane & 15;
  const int quad = lane >> 4;
  const float* X = side ? kv_x : q_x;
  const unsigned short* W0 = wt + (side ? 1 : 0) * 65536;  // wk : wq
  const unsigned short* W1 = wt + (side ? 2 : 3) * 65536;  // wv : wg
  f32x4 acc0[4], acc1[4];
  const f32x4 z = {0.f, 0.f, 0.f, 0.f};
#pragma unroll
  for (int nt = 0; nt < 4; ++nt) { acc0[nt] = z; acc1[nt] = z; }

  for (int k0 = 0; k0 < 256; k0 += 32) {
    const size_t abase = (size_t)(m0 + mrow) * 256 + k0 + quad * 8;
    const float4 a0 = *reinterpret_cast<const float4*>(X + abase);
    const float4 a1 = *reinterpret_cast<const float4*>(X + abase + 4);
    bf16x8 a;
    a[0] = (short)f2bf(a0.x); a[1] = (short)f2bf(a0.y);
    a[2] = (short)f2bf(a0.z); a[3] = (short)f2bf(a0.w);
    a[4] = (short)f2bf(a1.x); a[5] = (short)f2bf(a1.y);
    a[6] = (short)f2bf(a1.z); a[7] = (short)f2bf(a1.w);
#pragma unroll
    for (int nt = 0; nt < 4; ++nt) {
      const size_t wrow = (size_t)(n0 + nt * 16 + mrow) * 256 + k0 + quad * 8;
      const bf16x8 b0 = *reinterpret_cast<const bf16x8*>(W0 + wrow);
      const bf16x8 b1 = *reinterpret_cast<const bf16x8*>(W1 + wrow);
      acc0[nt] = __builtin_amdgcn_mfma_f32_16x16x32_bf16(a, b0, acc0[nt], 0, 0, 0);
      acc1[nt] = __builtin_amdgcn_mfma_f32_16x16x32_bf16(a, b1, acc1[nt], 0, 0, 0);
    }
  }

  const int b = m0 >> 10;
#pragma unroll
  for (int nt = 0; nt < 4; ++nt) {
    const int n = n0 + nt * 16 + mrow;  // output col
    const int h = n >> 5, c = n & 31;
    const float bgv = (side == 0) ? bg[n] : 0.f;
#pragma unroll
    for (int r = 0; r < 4; ++r) {
      const int row = m0 + quad * 4 + r;
      const int qp = row & 1023;
      const size_t o = ((size_t)(b * 8 + h) * 1024 + qp) * 32 + c;
      if (side == 0) {
        qhb[o] = f2bf(acc0[nt][r] * 0.17677669529663689f);  // 1/sqrt(32)
        const float zz = acc1[nt][r] + bgv;
        gws[(size_t)row * 256 + n] = 1.0f / (1.0f + __expf(-zz));
      } else {
        khb[o] = f2bf(acc0[nt][r]);
        vhb[o] = f2bf(acc1[nt][r]);
      }
    }
  }
}

// ------------- Kernel 2: MFMA flash attention + gate (R10) ---------------
// grid 1024 = B*H*(Q/32), 256 threads. Wave wv: qg=wv&1 (rows q0+qg*16..),
// kp=wv>>1 (K-tile parity). Per iter i: K tiles 2i,2i+1 staged via
// global_load_lds DMA (wave w: rows w*32..+31, 2 issues of 1024B into the
// row-linear ks[2][64][32]); V reg-staged transposed. Wave processes tile
// 2i+kp; bias C-init = R8's scattered per-wave loads. 8 iters. End:
// flash-merge (m,l,oa) across K-parity pairs via LDS; kp=0 stores.
__global__ __launch_bounds__(256) void attn_mfma(
    const unsigned short* __restrict__ qhb,
    const unsigned short* __restrict__ khb,
    const unsigned short* __restrict__ vhb,
    const float* __restrict__ bias_mask,
    const float* __restrict__ bias_pair,
    const float* __restrict__ gws, unsigned short* __restrict__ og) {
  __shared__ unsigned short ks[2][64 * 32];   // K-tile [parity][kpos][c], row-linear
  __shared__ unsigned short vsT[2][32 * 72];  // V-tile T [parity][c][kpos]
  __shared__ unsigned short ps[64 * 72];      // P bf16, per-wave 16-row bands
  const int x = blockIdx.x;
  const int b = x >> 8, h = (x >> 5) & 7, q0 = (x & 31) * 32;
  const int tid = threadIdx.x;
  const int wv = tid >> 6, lane = tid & 63, quad = lane >> 4, lr = lane & 15;
  const int qg = wv & 1;   // q-row half within the 32-row block
  const int kp = wv >> 1;  // K-tile parity this wave owns
  const int bh = b * 8 + h;

  // A-frag of Q for this wave (held in regs for all 8 K-tile iters).
  const bf16x8 aq = *reinterpret_cast<const bf16x8*>(
      qhb + ((size_t)bh * 1024 + q0 + qg * 16 + lr) * 32 + quad * 8);

  float m[4], l[4];
  f32x4 oa[2];
  const f32x4 zero4 = {0.f, 0.f, 0.f, 0.f};
  oa[0] = zero4; oa[1] = zero4;
#pragma unroll
  for (int r = 0; r < 4; ++r) { m[r] = -3e30f; l[r] = 0.f; }

  const float* bp = bias_pair + ((size_t)bh * 1024 + q0 + qg * 16) * 1024;
  const float* bm = bias_mask + (size_t)b * 1024;
  const unsigned short* kbase = khb + (size_t)bh * 32768;
  const unsigned short* vbase = vhb + (size_t)bh * 32768;

  for (int i = 0; i < 8; ++i) {
    __syncthreads();  // protect ks/vsT reuse (also drains prior DMA reads)
    // ---- K: fire-and-forget DMA. Wave wv covers rows wv*32..+31 of the
    //      128-row (2-tile) block; dest row rr lands at byte 64*rr, which
    //      is exactly ks[rr>>6][(rr&63)*32]. ----
#pragma unroll
    for (int j = 0; j < 2; ++j) {
      const int row0 = wv * 32 + j * 16;  // wave-uniform first row
      const unsigned short* g =
          kbase + (size_t)(i * 128 + row0 + (lane >> 2)) * 32 + (lane & 3) * 8;
      gload_lds16(g, &ks[0][0] + (size_t)row0 * 32);
    }
    // ---- V: reg-staged transpose scatter (2 chunks/thread) ----
#pragma unroll
    for (int j = 0; j < 2; ++j) {
      const int ch = tid * 2 + j;
      const int rr = ch >> 2, c8 = (ch & 3) * 8;
      const int p = rr >> 6, r64 = rr & 63;
      const bf16x8 vvv = *reinterpret_cast<const bf16x8*>(
          vbase + (size_t)(i * 128 + rr) * 32 + c8);
#pragma unroll
      for (int j2 = 0; j2 < 8; ++j2)
        vsT[p][(c8 + j2) * 72 + r64] = (unsigned short)vvv[j2];
    }
    __syncthreads();  // vmcnt(0)+lgkmcnt(0) drain: K DMA + V writes landed

    const int kk0 = (i * 2 + kp) * 64;  // this wave's K-tile origin

    // ---- scores: C preloaded with bias, then QK^T MFMA ----
    f32x4 s[4];
    float mk[4];
#pragma unroll
    for (int nt = 0; nt < 4; ++nt) mk[nt] = bm[kk0 + 16 * nt + lr];
#pragma unroll
    for (int nt = 0; nt < 4; ++nt) {
#pragma unroll
      for (int r = 0; r < 4; ++r)
        s[nt][r] = bp[(size_t)(quad * 4 + r) * 1024 + kk0 + 16 * nt + lr] + mk[nt];
      const bf16x8 bk = *reinterpret_cast<const bf16x8*>(
          &ks[kp][(16 * nt + lr) * 32 + quad * 8]);
      s[nt] = __builtin_amdgcn_mfma_f32_16x16x32_bf16(aq, bk, s[nt], 0, 0, 0);
    }

    // ---- online softmax (rows quad*4+r, reduce over 16-lane group) ----
#pragma unroll
    for (int r = 0; r < 4; ++r) {
      float mx = fmaxf(fmaxf(s[0][r], s[1][r]), fmaxf(s[2][r], s[3][r]));
      mx = fmaxf(mx, __shfl_xor(mx, 1));
      mx = fmaxf(mx, __shfl_xor(mx, 2));
      mx = fmaxf(mx, __shfl_xor(mx, 4));
      mx = fmaxf(mx, __shfl_xor(mx, 8));
      const float mn = fmaxf(m[r], mx);
      const float alpha = __expf(m[r] - mn);
      float rs = 0.f;
#pragma unroll
      for (int nt = 0; nt < 4; ++nt) {
        s[nt][r] = __expf(s[nt][r] - mn);
        rs += s[nt][r];
      }
      rs += __shfl_xor(rs, 1);
      rs += __shfl_xor(rs, 2);
      rs += __shfl_xor(rs, 4);
      rs += __shfl_xor(rs, 8);
      l[r] = l[r] * alpha + rs;
      m[r] = mn;
      oa[0][r] *= alpha;
      oa[1][r] *= alpha;
      const int ri = wv * 16 + quad * 4 + r;
#pragma unroll
      for (int nt = 0; nt < 4; ++nt)
        ps[ri * 72 + 16 * nt + lr] = f2bf(s[nt][r]);
    }
    // ps is per-wave; drain scatter writes before A-frag reads.
    asm volatile("s_waitcnt lgkmcnt(0)" ::: "memory");

    // ---- PV: A = P (own band), B = V^T (LDS buffer kp) ----
#pragma unroll
    for (int k0i = 0; k0i < 2; ++k0i) {
      const bf16x8 ap = *reinterpret_cast<const bf16x8*>(
          &ps[(wv * 16 + lr) * 72 + k0i * 32 + quad * 8]);
#pragma unroll
      for (int nt2 = 0; nt2 < 2; ++nt2) {
        const bf16x8 bv = *reinterpret_cast<const bf16x8*>(
            &vsT[kp][(nt2 * 16 + lr) * 72 + k0i * 32 + quad * 8]);
        oa[nt2] = __builtin_amdgcn_mfma_f32_16x16x32_bf16(ap, bv, oa[nt2], 0, 0, 0);
      }
    }
  }

  // ---- flash-merge across K-parity pairs (waves 2,3 -> waves 0,1) ----
  float* mrg = reinterpret_cast<float*>(ks);  // 8 KB scratch in ks region
  __syncthreads();  // last PV/QK reads done before overwriting ks
  if (kp == 1) {
    const int base = (qg * 64 + lane) * 16;
#pragma unroll
    for (int r = 0; r < 4; ++r) {
      mrg[base + r] = m[r];
      mrg[base + 4 + r] = l[r];
      mrg[base + 8 + r] = oa[0][r];
      mrg[base + 12 + r] = oa[1][r];
    }
  }
  __syncthreads();
  if (kp == 0) {
    const int base = (qg * 64 + lane) * 16;
#pragma unroll
    for (int r = 0; r < 4; ++r) {
      const float pm = mrg[base + r];
      const float pl = mrg[base + 4 + r];
      const float po0 = mrg[base + 8 + r];
      const float po1 = mrg[base + 12 + r];
      const float mn = fmaxf(m[r], pm);
      const float a0 = __expf(m[r] - mn);
      const float a1 = __expf(pm - mn);
      const float inv = 1.0f / (l[r] * a0 + pl * a1);
      const int qr = q0 + qg * 16 + quad * 4 + r;
      const size_t obase = ((size_t)b * 1024 + qr) * 256 + h * 32;
      const float o0 = oa[0][r] * a0 + po0 * a1;
      og[obase + lr] = f2bf(o0 * inv * gws[obase + lr]);
      const float o1 = oa[1][r] * a0 + po1 * a1;
      og[obase + 16 + lr] = f2bf(o1 * inv * gws[obase + 16 + lr]);
    }
  }
}

// ------------- Kernel 3: output projection (MFMA), fp32 out --------------
// grid 256: x = 16-row m-tile; wave w covers n-quarter w*64 (4 ntiles).
__global__ __launch_bounds__(256) void outproj_mfma(
    const unsigned short* __restrict__ og,
    const unsigned short* __restrict__ wt,
    const float* __restrict__ bo, float* __restrict__ out) {
  const int m0 = blockIdx.x * 16;
  const int lane = threadIdx.x & 63;
  const int n0 = (threadIdx.x >> 6) * 64;
  const int mrow = lane & 15;
  const int quad = lane >> 4;
  const unsigned short* W = wt + 4 * 65536;  // wo^T
  f32x4 acc[4];
  const f32x4 z = {0.f, 0.f, 0.f, 0.f};
#pragma unroll
  for (int nt = 0; nt < 4; ++nt) acc[nt] = z;

  for (int k0 = 0; k0 < 256; k0 += 32) {
    const bf16x8 a = *reinterpret_cast<const bf16x8*>(
        og + (size_t)(m0 + mrow) * 256 + k0 + quad * 8);
#pragma unroll
    for (int nt = 0; nt < 4; ++nt) {
      const bf16x8 b = *reinterpret_cast<const bf16x8*>(
          W + (size_t)(n0 + nt * 16 + mrow) * 256 + k0 + quad * 8);
      acc[nt] = __builtin_amdgcn_mfma_f32_16x16x32_bf16(a, b, acc[nt], 0, 0, 0);
    }
  }

#pragma unroll
  for (int nt = 0; nt < 4; ++nt) {
    const int n = n0 + nt * 16 + mrow;
    const float bov = bo[n];
#pragma unroll
    for (int r = 0; r < 4; ++r) {
      const int row = m0 + quad * 4 + r;
      out[(size_t)row * 256 + n] = acc[nt][r] + bov;
    }
  }
}

extern "C" void kernel_launch(void* const* d_in, const int* in_sizes, int n_in,
                              void* d_out, int out_size, void* d_ws,
                              size_t ws_size, hipStream_t stream) {
  (void)in_sizes; (void)n_in; (void)out_size; (void)ws_size;
  const float* q_x = (const float*)d_in[0];
  const float* kv_x = (const float*)d_in[1];
  const float* bias_mask = (const float*)d_in[2];
  const float* bias_pair = (const float*)d_in[3];
  const float* wq = (const float*)d_in[4];
  const float* wk = (const float*)d_in[5];
  const float* wv = (const float*)d_in[6];
  const float* wg = (const float*)d_in[7];
  const float* bg = (const float*)d_in[8];
  const float* wo = (const float*)d_in[9];
  const float* bo = (const float*)d_in[10];

  char* wsb = (char*)d_ws;
  unsigned short* wt  = (unsigned short*)(wsb);            // 640 KB
  unsigned short* qhb = (unsigned short*)(wsb + 655360);   // 2 MB
  unsigned short* khb = (unsigned short*)(wsb + 2752512);  // 2 MB
  unsigned short* vhb = (unsigned short*)(wsb + 4849664);  // 2 MB
  unsigned short* og  = (unsigned short*)(wsb + 6946816);  // 2 MB
  float* gws          = (float*)(wsb + 9043968);           // 4 MB

  transpose_conv<<<80, 256, 0, stream>>>(wq, wk, wv, wg, wo, wt);
  proj_mfma<<<dim3(256, 2), 256, 0, stream>>>(q_x, kv_x, wt, bg, qhb, khb,
                                              vhb, gws);
  attn_mfma<<<1024, 256, 0, stream>>>(qhb, khb, vhb, bias_mask, bias_pair,
                                      gws, og);
  outproj_mfma<<<256, 256, 0, stream>>>(og, wt, bo, (float*)d_out);
}